// Round 12
// baseline (98.216 us; speedup 1.0000x reference)
//
#include <hip/hip_runtime.h>
#include <hip/hip_bf16.h>

typedef short bf16x8 __attribute__((ext_vector_type(8)));
typedef float f32x16 __attribute__((ext_vector_type(16)));

#define NCOL  32
#define KS1   112             // f1 k-steps (K=1792, 16 per step, 4 s per step)
#define KS2   12              // f2 k-steps (K=192)
#define ESTR  264             // E row stride bytes (32 cols * 8B + 8 pad)

#define WP_OFF   0            // short [112][3][64][8] = 344064 B
#define W2P_OFF  344064       // short [12][3][64][8]  = 36864 B

#define MET_OFF  10824        // E region 41*264 = 10824; meta uint2[464] = 3712
#define SUM_OFF  14544        // transposed f32 [32 cols][196 dw] = 25088 (waves 0-3)
#define SUM2_OFF 39632        // same, waves 4-7
#define CSTR     784          // Sum col stride bytes (196 dw == 4 mod 32)
#define LDS_BYTES 64720

__device__ __forceinline__ unsigned short f2bf(float f) {
    union { float f; unsigned u; } v; v.f = f;
    unsigned r = v.u + 0x7FFFu + ((v.u >> 16) & 1u);
    return (unsigned short)(r >> 16);
}
__device__ __forceinline__ float bfl(unsigned u) {
    union { unsigned q; float f; } v; v.q = u << 16; return v.f;
}
__device__ __forceinline__ float bfh(unsigned u) {
    union { unsigned q; float f; } v; v.q = u & 0xffff0000u; return v.f;
}
__device__ __forceinline__ unsigned pk2(float a, float b) {
    __hip_bfloat162 h = __float22bfloat162_rn(make_float2(a, b));
    unsigned u; __builtin_memcpy(&u, &h, 4); return u;
}
__device__ __forceinline__ bf16x8 asbf(uint4 v) {
    union { uint4 u; bf16x8 b; } z; z.u = v; return z.b;
}
__device__ __forceinline__ f32x16 zero16() {
    f32x16 z;
#pragma unroll
    for (int i = 0; i < 16; ++i) z[i] = 0.f;
    return z;
}

// prep (validated r10/r11): A-frag layout for mfma_32x32x16.
// Wp[ks][mt][lane][8 shorts]; row = mt*32 + (lane&31); k = ks*16+(lane>>5)*8+v.
// Row r = o*4+p*2+reim (rows 80-83 = pbc C, 84-95 zero).
// k -> s=k>>2, t=k&3 (i=t&1 pol, cc=t>>1 re/im), plane j=i^p.
__global__ void prep_kernel(const float* __restrict__ W1,
                            const float* __restrict__ W2,
                            const float* __restrict__ pbcC,
                            unsigned short* __restrict__ Wp,
                            unsigned short* __restrict__ W2p, int S) {
    int idx = blockIdx.x * 256 + threadIdx.x;
    const int N1 = KS1 * 3 * 64 * 2;   // 43008
    const int N2 = KS2 * 3 * 64 * 2;   // 4608
    if (idx < N1) {
        int ks = idx / 384, rem = idx - ks * 384;
        int mt = rem >> 7; rem &= 127;
        int lane = rem >> 1, jh = rem & 1;
        int row = mt * 32 + (lane & 31);
        int kg  = ks * 16 + (lane >> 5) * 8 + jh * 4;
        int s   = kg >> 2;
        float2 wj0 = make_float2(0.f, 0.f), wj1 = make_float2(0.f, 0.f);
        int p = 0, r = 0;
        if (s < S) {
            if (row < 80) {
                int o = row >> 2; p = (row >> 1) & 1; r = row & 1;
                wj0 = ((const float2*)W1)[(size_t)(o * 2 + 0) * S + s];
                wj1 = ((const float2*)W1)[(size_t)(o * 2 + 1) * S + s];
            } else if (row < 84) {
                p = (row >> 1) & 1; r = row & 1;
                wj0 = ((const float2*)pbcC)[s];
            }
        }
        ushort4 h; unsigned short us[4];
#pragma unroll
        for (int t = 0; t < 4; ++t) {
            int i = t & 1, cc = t >> 1, j2 = i ^ p;
            float2 w = j2 ? wj1 : wj0;
            float v = (cc == 0) ? (r ? w.y : w.x) : (r ? w.x : -w.y);
            us[t] = f2bf(v);
        }
        h.x = us[0]; h.y = us[1]; h.z = us[2]; h.w = us[3];
        ((ushort4*)Wp)[idx] = h;
        return;
    }
    idx -= N1;
    if (idx < N2) {
        int ks = idx / 384, rem = idx - ks * 384;
        int mt = rem >> 7; rem &= 127;
        int lane = rem >> 1, jh = rem & 1;
        int row = mt * 32 + (lane & 31);
        int kg  = ks * 16 + (lane >> 5) * 8 + jh * 4;
        int m   = kg >> 2;
        float2 wj0 = make_float2(0.f, 0.f), wj1 = make_float2(0.f, 0.f);
        int p = 0, r = 0;
        if (m < 41 && row < 80) {
            int o = row >> 2; p = (row >> 1) & 1; r = row & 1;
            wj0 = ((const float2*)W2)[(o * 2 + 0) * 41 + m];
            wj1 = ((const float2*)W2)[(o * 2 + 1) * 41 + m];
        }
        ushort4 h; unsigned short us[4];
#pragma unroll
        for (int t = 0; t < 4; ++t) {
            int i = t & 1, cc = t >> 1, j2 = i ^ p;
            float2 w = j2 ? wj1 : wj0;
            float v = (cc == 0) ? (r ? w.y : w.x) : (r ? w.x : -w.y);
            us[t] = f2bf(v);
        }
        h.x = us[0]; h.y = us[1]; h.z = us[2]; h.w = us[3];
        ((ushort4*)W2p)[idx] = h;
    }
}

// 512-thr blocks: 32 cols, 8 waves = K-eighths -> 4 waves/SIMD (2 blocks/CU).
// Pipelined barrier-free K-loop; transposed Sum -> b128 reduction tail.
__global__ __launch_bounds__(512, 4) void eqsonn_kernel(
    const float* __restrict__ x, const float* __restrict__ task,
    const unsigned short* __restrict__ Wp,  // short [112][3][64][8]
    const unsigned short* __restrict__ W2p, // short [12][3][64][8]
    const int* __restrict__ m_idx, const int* __restrict__ n_idx,
    const float* __restrict__ b1, const float* __restrict__ b2,
    float* __restrict__ out, int B, int S)
{
    __shared__ alignas(16) char ldsb[LDS_BYTES];
    const int tid  = threadIdx.x;
    const int lane = tid & 63;
    const int w    = __builtin_amdgcn_readfirstlane(tid >> 6);   // 0..7
    const int col  = lane & 31;
    const int kha  = lane >> 5;
    const int b0   = blockIdx.x * NCOL;

    // ---- stage E bf16: row k at k*264 + col*8 ----
    for (int e = tid; e < 41 * NCOL; e += 512) {
        int bb = e / 41, k = e - bb * 41;
        int bs = b0 + bb; if (bs > B - 1) bs = B - 1;
        float4 v = ((const float4*)x)[(size_t)bs * 41 + k];
        ushort4 h;
        h.x = f2bf(v.x); h.y = f2bf(v.y); h.z = f2bf(v.z); h.w = f2bf(v.w);
        *(ushort4*)(ldsb + k * ESTR + bb * 8) = h;
    }
    // ---- stage meta byte-offsets, zero-padded to 464 ----
    if (tid < 464) {
        int m = 0, n = 0;
        if (tid < S) { m = m_idx[tid]; n = n_idx[tid]; }
        unsigned offM = (unsigned)((20 + m) * ESTR);
        unsigned offB = (unsigned)((20 + m + n) * ESTR);
        unsigned offN = (unsigned)((20 + n) * ESTR);
        *(uint2*)(ldsb + MET_OFF + tid * 8) = make_uint2(offM | (offB << 16), offN);
    }
    __syncthreads();

    const char* Ebase = ldsb + col * 8;
    auto ldM4 = [&](int ks) -> uint4 {
        return *(const uint4*)(ldsb + MET_OFF + (ks * 4 + kha * 2) * 8);
    };
    auto ldE = [&](unsigned off) -> uint2 {
        return *(const uint2*)(Ebase + off);
    };
    auto fbuild = [&](uint2 em, uint2 eq, uint2 en, unsigned& lo, unsigned& hi) {
        float m0r = bfl(em.x), m0i = bfh(em.x), m1r = bfl(em.y), m1i = bfh(em.y);
        float q0r = bfl(eq.x), q0i = bfh(eq.x), q1r = bfl(eq.y), q1i = bfh(eq.y);
        float n0r = bfl(en.x), n0i = bfh(en.x), n1r = bfl(en.y), n1i = bfh(en.y);
        float sr = m0r * q0r + m0i * q0i + m1r * q1r + m1i * q1i;
        float si = m0i * q0r - m0r * q0i + m1i * q1r - m1r * q1i;
        float F0r = sr * n0r - si * n0i, F0i = sr * n0i + si * n0r;
        float F1r = sr * n1r - si * n1i, F1i = sr * n1i + si * n1r;
        lo = pk2(F0r, F1r); hi = pk2(F0i, F1i);
    };

    // ---- f1 K-loop: 14 ksteps/wave, pipelined, barrier-free ----
    f32x16 ac0 = zero16(), ac1 = zero16(), ac2 = zero16();
    {
        const int ks0 = w * 14;
        const short* Wp16 = (const short*)Wp;
        uint4 M = ldM4(ks0);
        uint2 e0 = ldE(M.x & 0xffffu), e1 = ldE(M.x >> 16), e2 = ldE(M.y);
        uint2 e3 = ldE(M.z & 0xffffu), e4 = ldE(M.z >> 16), e5 = ldE(M.w);
        uint4 Mc = ldM4(ks0 + 1);
        const short* ap0 = Wp16 + (size_t)ks0 * 1536 + lane * 8;
        bf16x8 A0 = *(const bf16x8*)(ap0);
        bf16x8 A1 = *(const bf16x8*)(ap0 + 512);
        bf16x8 A2 = *(const bf16x8*)(ap0 + 1024);
        for (int ks = ks0; ks < ks0 + 14; ++ks) {
            int ksn = (ks + 1 < KS1) ? ks + 1 : KS1 - 1;
            const short* apn = Wp16 + (size_t)ksn * 1536 + lane * 8;
            bf16x8 N0 = *(const bf16x8*)(apn);
            bf16x8 N1 = *(const bf16x8*)(apn + 512);
            bf16x8 N2 = *(const bf16x8*)(apn + 1024);
            uint2 f0 = ldE(Mc.x & 0xffffu), f1v = ldE(Mc.x >> 16), f2v = ldE(Mc.y);
            uint2 f3 = ldE(Mc.z & 0xffffu), f4v = ldE(Mc.z >> 16), f5v = ldE(Mc.w);
            uint4 Mn = ldM4(ks + 2);
            unsigned g0, g1, g2, g3;
            fbuild(e0, e1, e2, g0, g1);
            fbuild(e3, e4, e5, g2, g3);
            bf16x8 bfr = asbf(make_uint4(g0, g1, g2, g3));
            ac0 = __builtin_amdgcn_mfma_f32_32x32x16_bf16(A0, bfr, ac0, 0, 0, 0);
            ac1 = __builtin_amdgcn_mfma_f32_32x32x16_bf16(A1, bfr, ac1, 0, 0, 0);
            ac2 = __builtin_amdgcn_mfma_f32_32x32x16_bf16(A2, bfr, ac2, 0, 0, 0);
            e0 = f0; e1 = f1v; e2 = f2v; e3 = f3; e4 = f4v; e5 = f5v; Mc = Mn;
            A0 = N0; A1 = N1; A2 = N2;
        }
    }

    // ---- f1 reduction: transposed Sum, b128 groups, pad rows skipped ----
    __syncthreads();
    char* Reg = ldsb + ((w < 4) ? SUM_OFF : SUM2_OFF);
    const int ph = w & 3;
    // C/D: row = (reg&3) + 8*(reg>>2) + 4*kha; regs g*4..g*4+3 = rows +0..3
    auto dump = [&](f32x16 a, int baserow, int limit, bool add) {
#pragma unroll
        for (int g = 0; g < 4; ++g) {
            int row = baserow + g * 8 + 4 * kha;
            if (row < limit) {
                float4* rp = (float4*)(Reg + col * CSTR + row * 4);
                float4 v = make_float4(a[g*4], a[g*4+1], a[g*4+2], a[g*4+3]);
                if (add) {
                    float4 o = *rp;
                    v.x += o.x; v.y += o.y; v.z += o.z; v.w += o.w;
                }
                *rp = v;
            }
        }
    };
    for (int p = 0; p < 4; ++p) {
        if (ph == p) {
            bool add = (p != 0);
            dump(ac0, 0, 192, add); dump(ac1, 32, 192, add); dump(ac2, 64, 84, add);
        }
        __syncthreads();
    }

    // ---- f2 (E region intact; acc regs reused) ----
    f32x16 bc0 = zero16(), bc1 = zero16(), bc2 = zero16();
    {
        const short* W216 = (const short*)W2p;
        for (int ks2 = w; ks2 < KS2; ks2 += 8) {
            const short* ap = W216 + (size_t)ks2 * 1536 + lane * 8;
            bf16x8 A0 = *(const bf16x8*)(ap);
            bf16x8 A1 = *(const bf16x8*)(ap + 512);
            bf16x8 A2 = *(const bf16x8*)(ap + 1024);
            unsigned g[4];
#pragma unroll
            for (int j = 0; j < 2; ++j) {
                int m = ks2 * 4 + kha * 2 + j;
                int mc = m < 41 ? m : 40;
                uint2 ue = *(const uint2*)(ldsb + mc * ESTR + col * 8);
                unsigned lo = (ue.x & 0xffffu) | (ue.y << 16);
                unsigned hi = (ue.x >> 16) | (ue.y & 0xffff0000u);
                if (m >= 41) { lo = 0u; hi = 0u; }
                g[j * 2] = lo; g[j * 2 + 1] = hi;
            }
            bf16x8 bfr = asbf(make_uint4(g[0], g[1], g[2], g[3]));
            bc0 = __builtin_amdgcn_mfma_f32_32x32x16_bf16(A0, bfr, bc0, 0, 0, 0);
            bc1 = __builtin_amdgcn_mfma_f32_32x32x16_bf16(A1, bfr, bc1, 0, 0, 0);
            bc2 = __builtin_amdgcn_mfma_f32_32x32x16_bf16(A2, bfr, bc2, 0, 0, 0);
        }
    }
    __syncthreads();
    for (int p = 0; p < 4; ++p) {
        if (ph == p) {
            bool add = (p != 0);
            dump(bc0, 96, 192, add); dump(bc1, 128, 192, add); dump(bc2, 160, 176, add);
        }
        __syncthreads();
    }

    // ---- epilogue: wave 0, lanes 0..31; reads both regions (no merge pass) ----
    if (w == 0 && lane < NCOL) {
        int c = lane;
        const char* R1 = ldsb + SUM_OFF  + c * CSTR;
        const char* R2 = ldsb + SUM2_OFF + c * CSTR;
        auto rd = [&](int row) -> float4 {
            float4 a = *(const float4*)(R1 + row * 4);
            float4 b = *(const float4*)(R2 + row * 4);
            return make_float4(a.x + b.x, a.y + b.y, a.z + b.z, a.w + b.w);
        };
        float4 pb = rd(80);   // rows 80-83 = pbc {pr0,pi0,pr1,pi1}
        float t0 = 0.f, t1 = 0.f, t2 = 0.f, t3 = 0.f;
#pragma unroll
        for (int o = 0; o < 10; ++o) {
            float b2r = b2[o * 2], b2i = b2[o * 2 + 1];
            float b1r = b1[o * 2], b1i = b1[o * 2 + 1];
            float4 A4 = rd(o * 4);
            float4 B4 = rd(96 + o * 4);
            float B0r = B4.x + b2r, B0i = B4.y + b2i;
            float B1r = B4.z + b2r, B1i = B4.w + b2i;
            float A0r = A4.x + b1r, A0i = A4.y + b1i;
            float A1r = A4.z + b1r, A1i = A4.w + b1i;
            // A*B*conj(B) + conj(A)*B*B = 2*Re(A*conj(B)) * B
            float g0 = 2.f * (A0r * B0r + A0i * B0i);
            t0 += g0 * B0r; t1 += g0 * B0i;
            float g1 = 2.f * (A1r * B1r + A1i * B1i);
            t2 += g1 * B1r; t3 += g1 * B1i;
        }
        int b = b0 + c;
        if (b < B) {
            float dbm = task[(size_t)b * 4];
            float P   = exp2f(dbm * 0.33219280948873623f) * 0.5f;  // 10^(dbm/10)/2
            float kP2 = 3.1622776601683794e-05f * P * P;           // 1e-4/sqrt(10)*P^2
            float4 Ec = ((const float4*)x)[(size_t)b * 41 + 20];   // fp32 center
            float4 o4;
            o4.x = Ec.x + P * pb.x + kP2 * t0;
            o4.y = Ec.y + P * pb.y + kP2 * t1;
            o4.z = Ec.z + P * pb.z + kP2 * t2;
            o4.w = Ec.w + P * pb.w + kP2 * t3;
            ((float4*)out)[b] = o4;
        }
    }
}

extern "C" void kernel_launch(void* const* d_in, const int* in_sizes, int n_in,
                              void* d_out, int out_size, void* d_ws, size_t ws_size,
                              hipStream_t stream) {
    const float* x     = (const float*)d_in[0];
    const float* task  = (const float*)d_in[1];
    const float* pbcC  = (const float*)d_in[2];
    const float* W1    = (const float*)d_in[3];
    const float* b1    = (const float*)d_in[4];
    const float* W2    = (const float*)d_in[5];
    const float* b2    = (const float*)d_in[6];
    const int*   m_idx = (const int*)d_in[7];
    const int*   n_idx = (const int*)d_in[8];
    float* out = (float*)d_out;

    int S = in_sizes[7];
    int B = in_sizes[0] / (41 * 2 * 2);

    char* ws = (char*)d_ws;
    unsigned short* Wp  = (unsigned short*)(ws + WP_OFF);
    unsigned short* W2p = (unsigned short*)(ws + W2P_OFF);

    int prep_n = KS1 * 3 * 64 * 2 + KS2 * 3 * 64 * 2;   // 47616
    prep_kernel<<<(prep_n + 255) / 256, 256, 0, stream>>>(W1, W2, pbcC, Wp, W2p, S);

    int grid = (B + NCOL - 1) / NCOL;
    eqsonn_kernel<<<grid, 512, 0, stream>>>(x, task, Wp, W2p, m_idx, n_idx,
                                            b1, b2, out, B, S);
}